// Round 18
// baseline (332.464 us; speedup 1.0000x reference)
//
#include <hip/hip_runtime.h>
#include <math.h>

#define LOG2PI 1.8378770664093453f
#define F32MIN (-3.4028234663852886e38f)
#define SMAX 384       // S (lane math assumes 384 = 64 lanes * 6 cols)
#define NW 38          // direction words per column = ceil(1200/32)

// ---------------------------------------------------------------------------
// Kernel 1: row sums of squares  lx2[b,t] = sum_c latent^2, lm2[b,s] = sum_c mean^2
__global__ __launch_bounds__(64) void k_sums(
    const float* __restrict__ latent, const float* __restrict__ mean,
    float* __restrict__ lx2, float* __restrict__ lm2, int BT, int BS, int C) {
  int row = blockIdx.x;
  int lane = threadIdx.x;
  const float* src;
  float* dst;
  if (row < BT) { src = latent + (size_t)row * C; dst = lx2 + row; }
  else          { src = mean + (size_t)(row - BT) * C; dst = lm2 + (row - BT); }
  float s = 0.f;
  for (int c = lane; c < C; c += 64) { float v = src[c]; s += v * v; }
  #pragma unroll
  for (int off = 32; off; off >>= 1) s += __shfl_down(s, off);
  if (lane == 0) *dst = s;
}

// ---------------------------------------------------------------------------
// Kernel 2: ll[b,t,s] = -0.5*(LOG2PI + lx2 - 2*dot + lm2) * attnmask
// R14's proven 64x64 tile / 4x4 micro-tile version. Masked-out tiles SKIPPED
// entirely (no write) — proven safe in R14.
__global__ __launch_bounds__(256) void k_scores(
    const float* __restrict__ latent, const float* __restrict__ mean,
    const float* __restrict__ lx2, const float* __restrict__ lm2,
    const int* __restrict__ textlen, const int* __restrict__ mellen,
    float* __restrict__ ll, int T, int S, int C) {
  int b  = blockIdx.z;
  int t0 = blockIdx.x * 64;
  int s0 = blockIdx.y * 64;
  int mel = mellen[b], txt = textlen[b];
  int tid = threadIdx.x;
  int ty = tid >> 4, tx = tid & 15;
  float* out = ll + ((size_t)b * T + t0) * S + s0;

  if (t0 >= mel || s0 >= txt || s0 > t0 + 63) return;

  __shared__ float At[16][64];
  __shared__ float Bt[16][64];
  float acc[4][4] = {};

  const float* Ab = latent + ((size_t)b * T + t0) * C;
  const float* Bb = mean + ((size_t)b * S + s0) * C;

  for (int kk = 0; kk < C; kk += 16) {
    int r  = tid >> 2;
    int cg = tid & 3;
    float4 a = (t0 + r < T) ? *(const float4*)(Ab + (size_t)r * C + kk + cg * 4)
                            : make_float4(0.f, 0.f, 0.f, 0.f);
    float4 bm = *(const float4*)(Bb + (size_t)r * C + kk + cg * 4);
    At[cg * 4 + 0][r] = a.x;  At[cg * 4 + 1][r] = a.y;
    At[cg * 4 + 2][r] = a.z;  At[cg * 4 + 3][r] = a.w;
    Bt[cg * 4 + 0][r] = bm.x; Bt[cg * 4 + 1][r] = bm.y;
    Bt[cg * 4 + 2][r] = bm.z; Bt[cg * 4 + 3][r] = bm.w;
    __syncthreads();
    #pragma unroll
    for (int k = 0; k < 16; ++k) {
      float4 a4 = *(const float4*)&At[k][ty * 4];
      float4 b4 = *(const float4*)&Bt[k][tx * 4];
      float av[4] = {a4.x, a4.y, a4.z, a4.w};
      float bv[4] = {b4.x, b4.y, b4.z, b4.w};
      #pragma unroll
      for (int i = 0; i < 4; ++i)
        #pragma unroll
        for (int j = 0; j < 4; ++j)
          acc[i][j] = fmaf(av[i], bv[j], acc[i][j]);
    }
    __syncthreads();
  }

  #pragma unroll
  for (int i = 0; i < 4; ++i) {
    int t = t0 + ty * 4 + i;
    if (t >= T) continue;
    float lx = lx2[(size_t)b * T + t];
    float4 o;
    float* po = &o.x;
    #pragma unroll
    for (int j = 0; j < 4; ++j) {
      int s = s0 + tx * 4 + j;
      float d = lx - 2.f * acc[i][j] + lm2[(size_t)b * S + s];
      float v = -0.5f * (LOG2PI + d);
      po[j] = (t < mel && s < txt) ? v : 0.f;
    }
    *(float4*)(out + (size_t)(ty * 4 + i) * S + tx * 4) = o;
  }
}

// ---------------------------------------------------------------------------
// DPP wave_shr:1 — lane l gets lane l-1's value, lane 0 gets -inf. Pure VALU.
__device__ __forceinline__ float dpp_shr1_neginf(float x) {
  int r = __builtin_amdgcn_update_dpp(
      __float_as_int(-INFINITY), __float_as_int(x),
      0x138 /*wave_shr:1*/, 0xf, 0xf, false);
  return __int_as_float(r);
}

// One MAS step — EXACT R9/R17 version (best measured). cmp/cndmask max,
// bool direction bits, non-inverted accumulation. r is wave-uniform.
template <bool MASKED>
__device__ __forceinline__ void mas_step(
    int t, int sbase, int r, const float2 A0, const float2 A1, const float2 A2,
    float& p0, float& p1, float& p2, float& p3, float& p4, float& p5,
    unsigned& a0, unsigned& a1, unsigned& a2, unsigned& a3, unsigned& a4,
    unsigned& a5) {
  float l0 = A0.x, l1 = A0.y, l2 = A1.x, l3 = A1.y, l4 = A2.x, l5 = A2.y;
  float pm1 = dpp_shr1_neginf(p5);
  bool c0 = p0 >= pm1, c1 = p1 >= p0, c2 = p2 >= p1;
  bool c3 = p3 >= p2,  c4 = p4 >= p3, c5 = p5 >= p4;
  float m0 = c0 ? p0 : pm1, m1 = c1 ? p1 : p0, m2 = c2 ? p2 : p1;
  float m3 = c3 ? p3 : p2,  m4 = c4 ? p4 : p3, m5 = c5 ? p5 : p4;
  a0 |= (unsigned)c0 << r; a1 |= (unsigned)c1 << r; a2 |= (unsigned)c2 << r;
  a3 |= (unsigned)c3 << r; a4 |= (unsigned)c4 << r; a5 |= (unsigned)c5 << r;
  if (MASKED) {
    p0 = (sbase + 0 <= t) ? m0 + l0 : F32MIN;
    p1 = (sbase + 1 <= t) ? m1 + l1 : F32MIN;
    p2 = (sbase + 2 <= t) ? m2 + l2 : F32MIN;
    p3 = (sbase + 3 <= t) ? m3 + l3 : F32MIN;
    p4 = (sbase + 4 <= t) ? m4 + l4 : F32MIN;
    p5 = (sbase + 5 <= t) ? m5 + l5 : F32MIN;
  } else {
    p0 = m0 + l0; p1 = m1 + l1; p2 = m2 + l2;
    p3 = m3 + l3; p4 = m4 + l4; p5 = m5 + l5;
  }
}

// ---------------------------------------------------------------------------
// Consumer: EXACT R9/R17 scan loop (best measured). Depth-2 named-register
// cadence, 2 steps/iter rolled loop, unpadded SMAX stride.
template <bool MASKED, int ROWS>
__device__ __forceinline__ void scan_chunk_lds(
    const float* __restrict__ rcur, int t0, int sbase,
    float& p0, float& p1, float& p2, float& p3, float& p4, float& p5,
    unsigned* __restrict__ dirT, int cw) {
  unsigned a0 = 0, a1 = 0, a2 = 0, a3 = 0, a4 = 0, a5 = 0;
  const float2* q = (const float2*)(rcur + sbase);   // row stride = 192 float2
  float2 A0 = q[0], A1 = q[1], A2 = q[2];
  #pragma unroll 1
  for (int r = 0; r < ROWS; r += 2) {
    const float2* qb = q + (size_t)(r + 1) * 192;
    float2 B0 = qb[0], B1 = qb[1], B2 = qb[2];
    mas_step<MASKED>(t0 + r, sbase, r, A0, A1, A2,
                     p0, p1, p2, p3, p4, p5, a0, a1, a2, a3, a4, a5);
    int rn = (r + 2 < ROWS) ? (r + 2) : (ROWS - 1);   // clamp: dummy in-bounds read
    const float2* qa = q + (size_t)rn * 192;
    A0 = qa[0]; A1 = qa[1]; A2 = qa[2];
    mas_step<MASKED>(t0 + r + 1, sbase, r + 1, B0, B1, B2,
                     p0, p1, p2, p3, p4, p5, a0, a1, a2, a3, a4, a5);
  }
  unsigned* dcol = dirT + (unsigned)sbase * NW + cw;
  dcol[0] = a0; dcol[NW] = a1; dcol[2 * NW] = a2;
  dcol[3 * NW] = a3; dcol[4 * NW] = a4; dcol[5 * NW] = a5;
}

// ---------------------------------------------------------------------------
// Async global->LDS, 16B per lane: LDS dest = wave-uniform base + lane*16,
// global src = per-lane address (guide §5; measured m03/m97 on gfx950).
#define GLOAD16(GP, LP) __builtin_amdgcn_global_load_lds( \
    (const __attribute__((address_space(1))) void*)(GP), \
    (__attribute__((address_space(3))) void*)(LP), 16, 0, 0)

// rule #18: counted/drain waits need a sched_barrier so consumers can't hoist.
#define WAIT_VM0() do { \
    asm volatile("s_waitcnt vmcnt(0)" ::: "memory"); \
    __builtin_amdgcn_sched_barrier(0); } while (0)

// ---------------------------------------------------------------------------
// Kernel 3: MAS forward scan + backtrack. ONE WAVE per batch (R18 A/B test:
// loader waves + per-chunk __syncthreads deleted; staging via
// global_load_lds issued a full chunk ahead, one vmcnt(0) per chunk).
// Scan loop is byte-identical to R17 (best measured) — this isolates the
// multi-wave producer/consumer machinery as the experimental variable.
// mel-cap: scan only ceil(mel/32) chunks (rows t >= mel never consumed).
// Assumes S == 384, T == 37*32 + 16.
__global__ __launch_bounds__(64, 1) void k_scan(
    const float* __restrict__ ll, const int* __restrict__ textlen,
    const int* __restrict__ mellen, int* __restrict__ pathidx, int T, int S) {
  int b = blockIdx.x;
  int lane = threadIdx.x;
  __shared__ float rows[2][32][SMAX];       // 98304 B
  __shared__ unsigned dirT[SMAX * NW];      // 58368 B, column-major bit-pack

  const float* llb = ll + (size_t)b * T * S;
  int mel = mellen[b], txt = textlen[b];
  int sbase = lane * 6;
  int nfull = T / 32;                        // 37
  int nch = (T + 31) / 32;                   // 38 (16-row tail)
  int nchb = (mel + 31) / 32;                // chunks actually needed
  if (nchb > nch) nchb = nch;
  float p0 = 0.f, p1 = 0.f, p2 = 0.f, p3 = 0.f, p4 = 0.f, p5 = 0.f;

  // prologue: stage chunk 0 (48 x 1KB async copies), drain once
  {
    const float* g = llb + lane * 4;
    float* d = &rows[0][0][0];
    #pragma unroll
    for (int k = 0; k < 48; ++k) GLOAD16(g + k * 256, d + k * 256);
  }
  WAIT_VM0();

  for (int c = 0; c < nchb; ++c) {
    int nxt = c + 1;
    if (nxt < nchb) {                       // issue next chunk's staging
      const float* g = llb + (size_t)nxt * 32 * S + lane * 4;
      float* d = &rows[nxt & 1][0][0];
      if (nxt < nfull) {
        #pragma unroll
        for (int k = 0; k < 48; ++k) GLOAD16(g + k * 256, d + k * 256);
      } else {
        #pragma unroll
        for (int k = 0; k < 24; ++k) GLOAD16(g + k * 256, d + k * 256);
      }
    }
    const float* rc = &rows[c & 1][0][0];
    int t0 = c * 32;
    if (c < 12) {      // chunks 0..11: t <= 383, per-cell s<=t masking
      scan_chunk_lds<true, 32>(rc, t0, sbase, p0, p1, p2, p3, p4, p5, dirT, c);
    } else if (c < nfull) {
      scan_chunk_lds<false, 32>(rc, t0, sbase, p0, p1, p2, p3, p4, p5, dirT, c);
    } else {
      scan_chunk_lds<false, 16>(rc, t0, sbase, p0, p1, p2, p3, p4, p5, dirT, c);
    }
    WAIT_VM0();                             // next chunk's data landed
  }

  size_t base = (size_t)b * T;
  int k0 = T - mel;  // rows j >= mel: direction forced to 1, i stays txt-1
  for (int k = lane; k < k0; k += 64) pathidx[base + k] = txt - 1;

  if (lane == 0) {
    // Verified backtrack: reload cached word only when the path moved (d==0)
    // or j crossed a 32-row word boundary.
    int i = txt - 1;
    int j = mel - 1;
    unsigned w = ~0u;
    bool reload = true;
    for (int k = k0; k < T; ++k) {
      pathidx[base + k] = i;
      if (reload) {
        int ii = (i < 0) ? i + S : i;   // JAX negative-index wrap
        ii = (ii < 0) ? 0 : ii;
        w = (ii < txt) ? dirT[ii * NW + (j >> 5)] : ~0u;  // outside mask: d=1
      }
      int d = (int)((w >> (j & 31)) & 1u);
      reload = (d == 0) | ((j & 31) == 0);
      i += d - 1;
      --j;
    }
  }
}

// ---------------------------------------------------------------------------
// Kernel 4 (fused scatter+rowloss): one wave per (b,k) row.
__global__ __launch_bounds__(256) void k_scatrow(
    float* __restrict__ attn, const float* __restrict__ latent,
    const float* __restrict__ mean, const int* __restrict__ pathidx,
    const int* __restrict__ textlen, const int* __restrict__ mellen,
    float* __restrict__ rowsum, int T, int S, int C) {
  int row = blockIdx.x * 4 + (threadIdx.x >> 6);
  int lane = threadIdx.x & 63;
  int b = row / T, k = row % T;
  int pi = pathidx[row];
  int mel = mellen[b], txt = textlen[b];
  bool on = (k < mel) && (pi >= 0) && (pi < S) && (pi < txt);

  float4* arow = (float4*)(attn + (size_t)row * S);
  int nf4 = S >> 2;
  for (int q = lane; q < nf4; q += 64) {
    float4 v = make_float4(0.f, 0.f, 0.f, 0.f);
    if (on && (pi >> 2) == q) (&v.x)[pi & 3] = 1.f;
    arow[q] = v;
  }

  const float* L = latent + (size_t)row * C;
  const float* M = mean + ((size_t)b * S + (on ? pi : 0)) * C;
  float s = 0.f;
  for (int c = lane; c < C; c += 64) {
    float d = L[c] - (on ? M[c] : 0.f);
    s += d * d;
  }
  #pragma unroll
  for (int off = 32; off; off >>= 1) s += __shfl_down(s, off);
  if (lane == 0) rowsum[row] = s;
}

// ---------------------------------------------------------------------------
// Kernel 5: per-batch durloss (histogram + log) and nll reduction
__global__ __launch_bounds__(256) void k_batch(
    const float* __restrict__ rowsum, const int* __restrict__ pathidx,
    const float* __restrict__ logdur, const int* __restrict__ textlen,
    const int* __restrict__ mellen, float* __restrict__ nllc,
    float* __restrict__ durc, int T, int S, int C) {
  int b = blockIdx.x;
  int tid = threadIdx.x;
  __shared__ int hist[512];
  __shared__ float red[256];
  int mel = mellen[b], txt = textlen[b];
  for (int s = tid; s < S; s += 256) hist[s] = 0;
  __syncthreads();
  for (int k = tid; k < T; k += 256) {
    int pi = pathidx[(size_t)b * T + k];
    if (k < mel && pi >= 0 && pi < S && pi < txt) atomicAdd(&hist[pi], 1);
  }
  __syncthreads();
  float part = 0.f;
  for (int s = tid; s < S; s += 256) {
    float cnt = (float)hist[s];
    float gt = logf(fmaxf(cnt, 1e-5f));
    gt = (s < txt) ? gt : 0.f;
    float d = logdur[(size_t)b * S + s] - gt;
    part += d * d;
  }
  red[tid] = part; __syncthreads();
  #pragma unroll
  for (int off = 128; off; off >>= 1) {
    if (tid < off) red[tid] += red[tid + off];
    __syncthreads();
  }
  if (tid == 0) durc[b] = red[0] / (float)mel;
  __syncthreads();
  part = 0.f;
  for (int k = tid; k < T; k += 256) part += rowsum[(size_t)b * T + k];
  red[tid] = part; __syncthreads();
  #pragma unroll
  for (int off = 128; off; off >>= 1) {
    if (tid < off) red[tid] += red[tid + off];
    __syncthreads();
  }
  if (tid == 0) nllc[b] = 0.5f * (LOG2PI + red[0]) / ((float)mel * (float)C);
}

// ---------------------------------------------------------------------------
// Kernel 6: loss = mean(nllc) + mean(durc)
__global__ __launch_bounds__(64) void k_final(
    const float* __restrict__ nllc, const float* __restrict__ durc,
    float* __restrict__ out, int B) {
  int lane = threadIdx.x;
  float v = (lane < B) ? (nllc[lane] + durc[lane]) : 0.f;
  #pragma unroll
  for (int off = 32; off; off >>= 1) v += __shfl_down(v, off);
  if (lane == 0) out[0] = v / (float)B;
}

// ---------------------------------------------------------------------------
extern "C" void kernel_launch(void* const* d_in, const int* in_sizes, int n_in,
                              void* d_out, int out_size, void* d_ws, size_t ws_size,
                              hipStream_t stream) {
  (void)n_in; (void)out_size; (void)ws_size;
  const float* latent = (const float*)d_in[0];
  const float* mean   = (const float*)d_in[1];
  const float* logdur = (const float*)d_in[2];
  const int*   textlen = (const int*)d_in[3];
  const int*   mellen  = (const int*)d_in[4];

  int B = in_sizes[3];
  int S = in_sizes[2] / B;
  int C = in_sizes[1] / (B * S);
  int T = in_sizes[0] / (B * C);

  float* out = (float*)d_out;
  float* ll = out + 1;  // reuse attn region [B*T*S] as ll scratch, overwritten later

  char* ws = (char*)d_ws;
  float* lx2    = (float*)ws;            // B*T
  float* lm2    = lx2 + (size_t)B * T;   // B*S
  int*   pathidx = (int*)(lm2 + (size_t)B * S);          // B*T
  float* rowsum  = (float*)(pathidx + (size_t)B * T);    // B*T
  float* nllc    = rowsum + (size_t)B * T;               // B
  float* durc    = nllc + B;                             // B

  k_sums<<<B * T + B * S, 64, 0, stream>>>(latent, mean, lx2, lm2, B * T, B * S, C);

  dim3 g2((T + 63) / 64, (S + 63) / 64, B);
  k_scores<<<g2, 256, 0, stream>>>(latent, mean, lx2, lm2, textlen, mellen, ll, T, S, C);

  k_scan<<<B, 64, 0, stream>>>(ll, textlen, mellen, pathidx, T, S);

  k_scatrow<<<(B * T) / 4, 256, 0, stream>>>(ll, latent, mean, pathidx, textlen,
                                             mellen, rowsum, T, S, C);

  k_batch<<<B, 256, 0, stream>>>(rowsum, pathidx, logdur, textlen, mellen, nllc, durc, T, S, C);

  k_final<<<1, 64, 0, stream>>>(nllc, durc, out, B);
}

// Round 19
// 298.054 us; speedup vs baseline: 1.1154x; 1.1154x over previous
//
#include <hip/hip_runtime.h>
#include <math.h>

#define LOG2PI 1.8378770664093453f
#define F32MIN (-3.4028234663852886e38f)
#define SMAX 384       // S (lane math assumes 384 = 64 lanes * 6 cols)
#define NW 38          // direction words per column = ceil(1200/32)

// ---------------------------------------------------------------------------
// Kernel 1: ll[b,t,s] = -0.5*(LOG2PI + lx2 - 2*dot + lm2) * attnmask
// R14's proven 64x64 tile / 4x4 micro-tile. Masked-out tiles SKIPPED (safe:
// scan stops at mel; cols >= txt propagate rightward only, bits never read;
// wholly s>t tiles lie in the scan's per-cell-masked region).
// R19: lx2/lm2 computed INLINE (they were only ever consumed here) — each
// thread accumulates sum-of-squares of its staged elements across the K loop,
// 2x shfl_xor reduces the 4 lanes of each row, result kept in LDS.
__global__ __launch_bounds__(256) void k_scores(
    const float* __restrict__ latent, const float* __restrict__ mean,
    const int* __restrict__ textlen, const int* __restrict__ mellen,
    float* __restrict__ ll, int T, int S, int C) {
  int b  = blockIdx.z;
  int t0 = blockIdx.x * 64;
  int s0 = blockIdx.y * 64;
  int mel = mellen[b], txt = textlen[b];
  int tid = threadIdx.x;
  int ty = tid >> 4, tx = tid & 15;
  float* out = ll + ((size_t)b * T + t0) * S + s0;

  if (t0 >= mel || s0 >= txt || s0 > t0 + 63) return;

  __shared__ float At[16][64];
  __shared__ float Bt[16][64];
  __shared__ float lxs[64];
  __shared__ float lms[64];
  float acc[4][4] = {};
  float asq = 0.f, bsq = 0.f;

  const float* Ab = latent + ((size_t)b * T + t0) * C;
  const float* Bb = mean + ((size_t)b * S + s0) * C;
  int r  = tid >> 2;
  int cg = tid & 3;

  for (int kk = 0; kk < C; kk += 16) {
    float4 a = (t0 + r < T) ? *(const float4*)(Ab + (size_t)r * C + kk + cg * 4)
                            : make_float4(0.f, 0.f, 0.f, 0.f);
    float4 bm = *(const float4*)(Bb + (size_t)r * C + kk + cg * 4);
    asq += a.x * a.x + a.y * a.y + a.z * a.z + a.w * a.w;
    bsq += bm.x * bm.x + bm.y * bm.y + bm.z * bm.z + bm.w * bm.w;
    At[cg * 4 + 0][r] = a.x;  At[cg * 4 + 1][r] = a.y;
    At[cg * 4 + 2][r] = a.z;  At[cg * 4 + 3][r] = a.w;
    Bt[cg * 4 + 0][r] = bm.x; Bt[cg * 4 + 1][r] = bm.y;
    Bt[cg * 4 + 2][r] = bm.z; Bt[cg * 4 + 3][r] = bm.w;
    __syncthreads();
    #pragma unroll
    for (int k = 0; k < 16; ++k) {
      float4 a4 = *(const float4*)&At[k][ty * 4];
      float4 b4 = *(const float4*)&Bt[k][tx * 4];
      float av[4] = {a4.x, a4.y, a4.z, a4.w};
      float bv[4] = {b4.x, b4.y, b4.z, b4.w};
      #pragma unroll
      for (int i = 0; i < 4; ++i)
        #pragma unroll
        for (int j = 0; j < 4; ++j)
          acc[i][j] = fmaf(av[i], bv[j], acc[i][j]);
    }
    __syncthreads();
  }

  // finalize row sums: reduce the 4 lanes (colgroups) of each row
  asq += __shfl_xor(asq, 1); asq += __shfl_xor(asq, 2);
  bsq += __shfl_xor(bsq, 1); bsq += __shfl_xor(bsq, 2);
  if (cg == 0) { lxs[r] = asq; lms[r] = bsq; }
  __syncthreads();

  #pragma unroll
  for (int i = 0; i < 4; ++i) {
    int t = t0 + ty * 4 + i;
    if (t >= T) continue;
    float lx = lxs[ty * 4 + i];
    float4 o;
    float* po = &o.x;
    #pragma unroll
    for (int j = 0; j < 4; ++j) {
      int s = s0 + tx * 4 + j;
      float d = lx - 2.f * acc[i][j] + lms[tx * 4 + j];
      float v = -0.5f * (LOG2PI + d);
      po[j] = (t < mel && s < txt) ? v : 0.f;
    }
    *(float4*)(out + (size_t)(ty * 4 + i) * S + tx * 4) = o;
  }
}

// ---------------------------------------------------------------------------
// DPP wave_shr:1 — lane l gets lane l-1's value, lane 0 gets -inf. Pure VALU.
__device__ __forceinline__ float dpp_shr1_neginf(float x) {
  int r = __builtin_amdgcn_update_dpp(
      __float_as_int(-INFINITY), __float_as_int(x),
      0x138 /*wave_shr:1*/, 0xf, 0xf, false);
  return __int_as_float(r);
}

// One MAS step — EXACT R9/R17 version (best measured). cmp/cndmask max,
// bool direction bits, non-inverted accumulation. r is wave-uniform.
template <bool MASKED>
__device__ __forceinline__ void mas_step(
    int t, int sbase, int r, const float2 A0, const float2 A1, const float2 A2,
    float& p0, float& p1, float& p2, float& p3, float& p4, float& p5,
    unsigned& a0, unsigned& a1, unsigned& a2, unsigned& a3, unsigned& a4,
    unsigned& a5) {
  float l0 = A0.x, l1 = A0.y, l2 = A1.x, l3 = A1.y, l4 = A2.x, l5 = A2.y;
  float pm1 = dpp_shr1_neginf(p5);
  bool c0 = p0 >= pm1, c1 = p1 >= p0, c2 = p2 >= p1;
  bool c3 = p3 >= p2,  c4 = p4 >= p3, c5 = p5 >= p4;
  float m0 = c0 ? p0 : pm1, m1 = c1 ? p1 : p0, m2 = c2 ? p2 : p1;
  float m3 = c3 ? p3 : p2,  m4 = c4 ? p4 : p3, m5 = c5 ? p5 : p4;
  a0 |= (unsigned)c0 << r; a1 |= (unsigned)c1 << r; a2 |= (unsigned)c2 << r;
  a3 |= (unsigned)c3 << r; a4 |= (unsigned)c4 << r; a5 |= (unsigned)c5 << r;
  if (MASKED) {
    p0 = (sbase + 0 <= t) ? m0 + l0 : F32MIN;
    p1 = (sbase + 1 <= t) ? m1 + l1 : F32MIN;
    p2 = (sbase + 2 <= t) ? m2 + l2 : F32MIN;
    p3 = (sbase + 3 <= t) ? m3 + l3 : F32MIN;
    p4 = (sbase + 4 <= t) ? m4 + l4 : F32MIN;
    p5 = (sbase + 5 <= t) ? m5 + l5 : F32MIN;
  } else {
    p0 = m0 + l0; p1 = m1 + l1; p2 = m2 + l2;
    p3 = m3 + l3; p4 = m4 + l4; p5 = m5 + l5;
  }
}

// ---------------------------------------------------------------------------
// Consumer: EXACT R9/R17 scan loop (best measured). Depth-2 named-register
// cadence, 2 steps/iter rolled loop, unpadded SMAX stride.
template <bool MASKED, int ROWS>
__device__ __forceinline__ void scan_chunk_lds(
    const float* __restrict__ rcur, int t0, int sbase,
    float& p0, float& p1, float& p2, float& p3, float& p4, float& p5,
    unsigned* __restrict__ dirT, int cw) {
  unsigned a0 = 0, a1 = 0, a2 = 0, a3 = 0, a4 = 0, a5 = 0;
  const float2* q = (const float2*)(rcur + sbase);   // row stride = 192 float2
  float2 A0 = q[0], A1 = q[1], A2 = q[2];
  #pragma unroll 1
  for (int r = 0; r < ROWS; r += 2) {
    const float2* qb = q + (size_t)(r + 1) * 192;
    float2 B0 = qb[0], B1 = qb[1], B2 = qb[2];
    mas_step<MASKED>(t0 + r, sbase, r, A0, A1, A2,
                     p0, p1, p2, p3, p4, p5, a0, a1, a2, a3, a4, a5);
    int rn = (r + 2 < ROWS) ? (r + 2) : (ROWS - 1);   // clamp: dummy in-bounds read
    const float2* qa = q + (size_t)rn * 192;
    A0 = qa[0]; A1 = qa[1]; A2 = qa[2];
    mas_step<MASKED>(t0 + r + 1, sbase, r + 1, B0, B1, B2,
                     p0, p1, p2, p3, p4, p5, a0, a1, a2, a3, a4, a5);
  }
  unsigned* dcol = dirT + (unsigned)sbase * NW + cw;
  dcol[0] = a0; dcol[NW] = a1; dcol[2 * NW] = a2;
  dcol[3 * NW] = a3; dcol[4 * NW] = a4; dcol[5 * NW] = a5;
}

// ---------------------------------------------------------------------------
// Kernel 2: MAS forward scan + backtrack. One block (4 waves) per batch.
// EXACT R17 structure (best measured 211us): wave 0 scans from LDS, waves
// 1-3 double-buffer the next 32-row ll chunk, mel-cap on chunk count
// (rows t >= mel never consumed; loaders share the cap so barriers match).
// Assumes S == 384, T == 37*32 + 16.
__global__ __launch_bounds__(256, 1) void k_scan(
    const float* __restrict__ ll, const int* __restrict__ textlen,
    const int* __restrict__ mellen, int* __restrict__ pathidx, int T, int S) {
  int b = blockIdx.x;
  int tid = threadIdx.x;
  int lane = tid & 63;
  __shared__ float rows[2][32][SMAX];       // 98304 B (unpadded — R9 config)
  __shared__ unsigned dirT[SMAX * NW];      // 58368 B, column-major bit-pack

  const float* llb = ll + (size_t)b * T * S;
  int mel = mellen[b], txt = textlen[b];
  int sbase = lane * 6;
  int nfull = T / 32;                        // 37
  int nch = (T + 31) / 32;                   // 38 (16-row tail)
  int nchb = (mel + 31) / 32;                // chunks actually needed
  if (nchb > nch) nchb = nch;
  float p0 = 0.f, p1 = 0.f, p2 = 0.f, p3 = 0.f, p4 = 0.f, p5 = 0.f;

  // prologue: loader waves fill chunk 0 (32*384 floats = 3072 float4, 192x16)
  if (tid >= 64) {
    int lid = tid - 64;
    const float4* g = (const float4*)llb;
    float4* d = (float4*)&rows[0][0][0];
    #pragma unroll
    for (int k = 0; k < 16; ++k) d[k * 192 + lid] = g[k * 192 + lid];
  }
  __syncthreads();

  for (int c = 0; c < nchb; ++c) {
    if (tid >= 64) {
      int nxt = c + 1;
      if (nxt < nchb) {
        int lid = tid - 64;
        const float4* g = (const float4*)(llb + (size_t)nxt * 32 * S);
        float4* d = (float4*)&rows[nxt & 1][0][0];
        if (nxt < nfull) {
          float4 stg[16];
          #pragma unroll
          for (int k = 0; k < 16; ++k) stg[k] = g[k * 192 + lid];
          #pragma unroll
          for (int k = 0; k < 16; ++k) d[k * 192 + lid] = stg[k];
        } else {
          float4 stg[8];
          #pragma unroll
          for (int k = 0; k < 8; ++k) stg[k] = g[k * 192 + lid];
          #pragma unroll
          for (int k = 0; k < 8; ++k) d[k * 192 + lid] = stg[k];
        }
      }
    } else {
      const float* rc = &rows[c & 1][0][0];
      int t0 = c * 32;
      if (c < 12) {      // chunks 0..11: t <= 383, per-cell s<=t masking
        scan_chunk_lds<true, 32>(rc, t0, sbase, p0, p1, p2, p3, p4, p5, dirT, c);
      } else if (c < nfull) {
        scan_chunk_lds<false, 32>(rc, t0, sbase, p0, p1, p2, p3, p4, p5, dirT, c);
      } else {
        scan_chunk_lds<false, 16>(rc, t0, sbase, p0, p1, p2, p3, p4, p5, dirT, c);
      }
    }
    __syncthreads();
  }

  if (tid >= 64) return;

  size_t base = (size_t)b * T;
  int k0 = T - mel;  // rows j >= mel: direction forced to 1, i stays txt-1
  for (int k = lane; k < k0; k += 64) pathidx[base + k] = txt - 1;

  if (lane == 0) {
    // Verified backtrack: reload cached word only when the path moved (d==0)
    // or j crossed a 32-row word boundary.
    int i = txt - 1;
    int j = mel - 1;
    unsigned w = ~0u;
    bool reload = true;
    for (int k = k0; k < T; ++k) {
      pathidx[base + k] = i;
      if (reload) {
        int ii = (i < 0) ? i + S : i;   // JAX negative-index wrap
        ii = (ii < 0) ? 0 : ii;
        w = (ii < txt) ? dirT[ii * NW + (j >> 5)] : ~0u;  // outside mask: d=1
      }
      int d = (int)((w >> (j & 31)) & 1u);
      reload = (d == 0) | ((j & 31) == 0);
      i += d - 1;
      --j;
    }
  }
}

// ---------------------------------------------------------------------------
// Kernel 3 (fused scatter+rowloss): one wave per (b,k) row.
// Writes the one-hot attn row (full coverage, overwrites ll scratch) AND
// computes rowsum[b,k] = sum_c (latent - aligned)^2 in the same pass.
__global__ __launch_bounds__(256) void k_scatrow(
    float* __restrict__ attn, const float* __restrict__ latent,
    const float* __restrict__ mean, const int* __restrict__ pathidx,
    const int* __restrict__ textlen, const int* __restrict__ mellen,
    float* __restrict__ rowsum, int T, int S, int C) {
  int row = blockIdx.x * 4 + (threadIdx.x >> 6);
  int lane = threadIdx.x & 63;
  int b = row / T, k = row % T;
  int pi = pathidx[row];
  int mel = mellen[b], txt = textlen[b];
  bool on = (k < mel) && (pi >= 0) && (pi < S) && (pi < txt);

  float4* arow = (float4*)(attn + (size_t)row * S);
  int nf4 = S >> 2;
  for (int q = lane; q < nf4; q += 64) {
    float4 v = make_float4(0.f, 0.f, 0.f, 0.f);
    if (on && (pi >> 2) == q) (&v.x)[pi & 3] = 1.f;
    arow[q] = v;
  }

  const float* L = latent + (size_t)row * C;
  const float* M = mean + ((size_t)b * S + (on ? pi : 0)) * C;
  float s = 0.f;
  for (int c = lane; c < C; c += 64) {
    float d = L[c] - (on ? M[c] : 0.f);
    s += d * d;
  }
  #pragma unroll
  for (int off = 32; off; off >>= 1) s += __shfl_down(s, off);
  if (lane == 0) rowsum[row] = s;
}

// ---------------------------------------------------------------------------
// Kernel 4: per-batch durloss (histogram + log) and nll reduction
__global__ __launch_bounds__(256) void k_batch(
    const float* __restrict__ rowsum, const int* __restrict__ pathidx,
    const float* __restrict__ logdur, const int* __restrict__ textlen,
    const int* __restrict__ mellen, float* __restrict__ nllc,
    float* __restrict__ durc, int T, int S, int C) {
  int b = blockIdx.x;
  int tid = threadIdx.x;
  __shared__ int hist[512];
  __shared__ float red[256];
  int mel = mellen[b], txt = textlen[b];
  for (int s = tid; s < S; s += 256) hist[s] = 0;
  __syncthreads();
  for (int k = tid; k < T; k += 256) {
    int pi = pathidx[(size_t)b * T + k];
    if (k < mel && pi >= 0 && pi < S && pi < txt) atomicAdd(&hist[pi], 1);
  }
  __syncthreads();
  float part = 0.f;
  for (int s = tid; s < S; s += 256) {
    float cnt = (float)hist[s];
    float gt = logf(fmaxf(cnt, 1e-5f));
    gt = (s < txt) ? gt : 0.f;
    float d = logdur[(size_t)b * S + s] - gt;
    part += d * d;
  }
  red[tid] = part; __syncthreads();
  #pragma unroll
  for (int off = 128; off; off >>= 1) {
    if (tid < off) red[tid] += red[tid + off];
    __syncthreads();
  }
  if (tid == 0) durc[b] = red[0] / (float)mel;
  __syncthreads();
  part = 0.f;
  for (int k = tid; k < T; k += 256) part += rowsum[(size_t)b * T + k];
  red[tid] = part; __syncthreads();
  #pragma unroll
  for (int off = 128; off; off >>= 1) {
    if (tid < off) red[tid] += red[tid + off];
    __syncthreads();
  }
  if (tid == 0) nllc[b] = 0.5f * (LOG2PI + red[0]) / ((float)mel * (float)C);
}

// ---------------------------------------------------------------------------
// Kernel 5: loss = mean(nllc) + mean(durc)
__global__ __launch_bounds__(64) void k_final(
    const float* __restrict__ nllc, const float* __restrict__ durc,
    float* __restrict__ out, int B) {
  int lane = threadIdx.x;
  float v = (lane < B) ? (nllc[lane] + durc[lane]) : 0.f;
  #pragma unroll
  for (int off = 32; off; off >>= 1) v += __shfl_down(v, off);
  if (lane == 0) out[0] = v / (float)B;
}

// ---------------------------------------------------------------------------
extern "C" void kernel_launch(void* const* d_in, const int* in_sizes, int n_in,
                              void* d_out, int out_size, void* d_ws, size_t ws_size,
                              hipStream_t stream) {
  (void)n_in; (void)out_size; (void)ws_size;
  const float* latent = (const float*)d_in[0];
  const float* mean   = (const float*)d_in[1];
  const float* logdur = (const float*)d_in[2];
  const int*   textlen = (const int*)d_in[3];
  const int*   mellen  = (const int*)d_in[4];

  int B = in_sizes[3];
  int S = in_sizes[2] / B;
  int C = in_sizes[1] / (B * S);
  int T = in_sizes[0] / (B * C);

  float* out = (float*)d_out;
  float* ll = out + 1;  // reuse attn region [B*T*S] as ll scratch, overwritten later

  char* ws = (char*)d_ws;
  int*   pathidx = (int*)ws;                             // B*T
  float* rowsum  = (float*)(pathidx + (size_t)B * T);    // B*T
  float* nllc    = rowsum + (size_t)B * T;               // B
  float* durc    = nllc + B;                             // B

  dim3 g2((T + 63) / 64, (S + 63) / 64, B);
  k_scores<<<g2, 256, 0, stream>>>(latent, mean, textlen, mellen, ll, T, S, C);

  k_scan<<<B, 256, 0, stream>>>(ll, textlen, mellen, pathidx, T, S);

  k_scatrow<<<(B * T) / 4, 256, 0, stream>>>(ll, latent, mean, pathidx, textlen,
                                             mellen, rowsum, T, S, C);

  k_batch<<<B, 256, 0, stream>>>(rowsum, pathidx, logdur, textlen, mellen, nllc, durc, T, S, C);

  k_final<<<1, 64, 0, stream>>>(nllc, durc, out, B);
}